// Round 9
// baseline (267.744 us; speedup 1.0000x reference)
//
#include <hip/hip_runtime.h>

// BoxFilter: 21x21 all-ones box, circular pad, x: f32[8,1,2048,2048].
// v8b: rolling-ring staging (identical resubmit; round-8 bench was an infra
// failure, kernel never ran). v2/v5/v7 all saturate ~5 TB/s of TA volume incl.
// L2/L3-served halo re-reads -> the lever is VOLUME. Each block owns a 128x256
// panel = eight 32-row tiles; raw rows staged ONCE into a 64-row LDS ring
// (slot = (j+10)&63) via global_load_lds (segments slot-contiguous, linear
// dest). Read volume 259->171 MB. Colsum buffer 16 rows; LDS 48.9 KB -> 3/CU.

#define HH 2048
#define WW 2048
#define RAD 10
#define DIAM 21
#define TW 128
#define NQ 38              // quads per raw row (152 cols: w0-12 .. w0+139)
#define RING 64            // ring rows
#define RW (NQ * 4)        // 152 floats per ring row
#define NT 8               // tiles per block (32 rows each)
#define PANEL (32 * NT)    // 256 rows per block
#define SSTR 156           // colsum row stride (floats)

typedef float nfloat4 __attribute__((ext_vector_type(4)));
typedef const __attribute__((address_space(1))) void* gp_t;
typedef __attribute__((address_space(3))) void* lp_t;

// Stage NR raw rows with j+10 = S0..S0+NR-1 into ring slots (S0&63..): caller
// guarantees no 64-wrap inside the segment. Dest = wave-uniform base + lane*16.
#define STAGE(S0, NR)                                                         \
  do {                                                                        \
    const int slotbase = (S0) & 63;                                           \
    _Pragma("unroll")                                                         \
    for (int rd = 0; rd < ((NR) * NQ + 255) / 256; ++rd) {                    \
      const int q = rd * 256 + tid;                                           \
      if (q < (NR) * NQ) {                                                    \
        const int rr = q / NQ;                                                \
        const int c = q - rr * NQ;                                            \
        const int grow = (hbase + (S0) + rr - 10) & (HH - 1);                 \
        const int gcol = (w0 - 12 + 4 * c) & (WW - 1);                        \
        const float* src = xp + (size_t)grow * WW + gcol;                     \
        float* dst = (float*)&ring[slotbase * RW + (rd * 256 + wbase) * 4];   \
        __builtin_amdgcn_global_load_lds((gp_t)(uintptr_t)src,                \
                                         (lp_t)(uintptr_t)dst, 16, 0, 0);     \
      }                                                                       \
    }                                                                         \
  } while (0)

__global__ __launch_bounds__(256) void box_filter_v8(
    const float* __restrict__ x, float* __restrict__ out) {
  __shared__ float ring[RING * RW];  // 38912 B raw-row ring
  __shared__ float sCS[16 * SSTR];   // 9984 B colsum (one 16-row group)

  const int n = blockIdx.z;
  const int hbase = blockIdx.y * PANEL;
  const int w0 = blockIdx.x * TW;
  const float* __restrict__ xp = x + (size_t)n * (HH * WW);
  float* __restrict__ op = out + (size_t)n * (HH * WW);
  const int tid = threadIdx.x;
  const int wbase = tid & ~63;

  // Prologue: j = -10..9 -> slots 0..19.
  STAGE(0, 20);

  for (int t = 0; t < NT; ++t) {
    const int tbase = 32 * t;
    // New rows for this tile: j+10 = 32t+20 .. 32t+51, as two segments that
    // never cross a 64-slot wrap internally (starts at {20,52} and {32,0}).
    STAGE(32 * t + 20, 12);
    STAGE(32 * t + 32, 20);
    __syncthreads();  // stage complete (drains vmcnt); also fences B1(t-1)/A0

#pragma unroll
    for (int g = 0; g < 2; ++g) {
      // ---- Phase A: vertical sliding sums from ring. 38 quads x 2 subgroups
      // of 8 rows = 76 tasks; each 35 b128 ring reads + 8 colsum writes.
      if (tid < 2 * NQ) {
        const int c4 = tid % NQ;
        const int sg = tid / NQ;
        const int p0 = tbase + 16 * g + 8 * sg;  // first output row (panel-rel)
        const int cof = c4 * 4;
        nfloat4 s = *(const nfloat4*)&ring[(p0 & 63) * RW + cof];
#pragma unroll
        for (int k = 1; k < DIAM; ++k)
          s += *(const nfloat4*)&ring[((p0 + k) & 63) * RW + cof];
        *(nfloat4*)&sCS[(8 * sg) * SSTR + cof] = s;
#pragma unroll
        for (int i = 1; i < 8; ++i) {
          s += *(const nfloat4*)&ring[((p0 + i + 20) & 63) * RW + cof] -
               *(const nfloat4*)&ring[((p0 + i - 1) & 63) * RW + cof];
          *(nfloat4*)&sCS[(8 * sg + i) * SSTR + cof] = s;
        }
      }
      __syncthreads();  // colsums ready

      // ---- Phase B: horizontal sliding sums. 16 rows x 8 chunks = 128 tasks.
      if (tid < 128) {
        const int r = tid >> 3;  // 0..15 (buffer row)
        const int cg = tid & 7;  // 0..7
        const int p = tbase + 16 * g + r;  // panel-relative output row
        const float* rowp = &sCS[r * SSTR + 16 * cg];
        float* orow = &op[(size_t)(hbase + p) * WW + w0 + 16 * cg];
        __align__(16) float w[40];
#pragma unroll
        for (int k = 0; k < 10; ++k)
          *(nfloat4*)&w[4 * k] = *(const nfloat4*)&rowp[4 * k];
        float s = w[2];
#pragma unroll
        for (int k = 3; k <= 22; ++k) s += w[k];
        float o[16];
        o[0] = s;
#pragma unroll
        for (int j = 1; j < 16; ++j) {
          s += w[j + 22] - w[j + 1];
          o[j] = s;
        }
#pragma unroll
        for (int q = 0; q < 4; ++q) {
          nfloat4 ov = {o[4 * q], o[4 * q + 1], o[4 * q + 2], o[4 * q + 3]};
          *(nfloat4*)&orow[4 * q] = ov;
        }
      }
      if (g == 0) __syncthreads();  // B0 reads done before A1 overwrites sCS
    }
    // No trailing barrier: next iter's stage touches only dead ring slots,
    // and its __syncthreads fences B1-reads vs next A0's sCS writes.
  }
}

extern "C" void kernel_launch(void* const* d_in, const int* in_sizes, int n_in,
                              void* d_out, int out_size, void* d_ws, size_t ws_size,
                              hipStream_t stream) {
  const float* x = (const float*)d_in[0];
  float* out = (float*)d_out;
  dim3 grid(WW / TW, HH / PANEL, 8);  // 16 x 8 x 8 = 1024 blocks
  dim3 block(256);
  hipLaunchKernelGGL(box_filter_v8, grid, block, 0, stream, x, out);
}